// Round 2
// baseline (93.684 us; speedup 1.0000x reference)
//
#include <hip/hip_runtime.h>

// Ewald reciprocal: B=2, N=4096 atoms, NK=4096 k-vectors, all f32.
// out = concat(0.5*q*phi, phi), each B*N floats.

constexpr int B   = 2;
constexpr int N   = 4096;
constexpr int NK  = 4096;
constexpr int TPB = 256;
constexpr int NS1 = 64;          // atom-axis split for structure-factor pass
constexpr int NS2 = 64;          // k-axis split for field pass
constexpr int TILE1 = N / NS1;   // 64 atoms per sf block
constexpr int TILE2 = NK / NS2;  // 64 k-vectors per recip block

// workspace layout (float offsets)
constexpr int KT4 = 0;                 // NK*4   : (kt0,kt1,kt2,0) per k
constexpr int AT4 = KT4 + NK * 4;      // B*N*4  : (x,y,z,q) per atom
constexpr int SRE = AT4 + B * N * 4;   // B*NK   : zeroed, atomic acc
constexpr int SIM = SRE + B * NK;      // B*NK   : zeroed, atomic acc
constexpr int REC = SIM + B * NK;      // B*N    : zeroed, atomic acc
constexpr int SP  = REC + B * N;       // B*NK*2 : (ef*Sre, ef*Sim) packed
constexpr int ZERO_FLOATS = 2 * B * NK + B * N;  // SRE..REC contiguous

__global__ __launch_bounds__(256) void prep_kernel(const float* __restrict__ coords,
                                                   const float* __restrict__ q,
                                                   const float* __restrict__ cinv,
                                                   const float* __restrict__ kvec,
                                                   float* __restrict__ ws) {
    int i = blockIdx.x * TPB + threadIdx.x;   // 0 .. B*N-1
    if (i < NK) {
        float k0 = kvec[i * 3 + 0], k1 = kvec[i * 3 + 1], k2 = kvec[i * 3 + 2];
        // kt[j] = sum_d kvec[k,d] * cinv[d,j]  (theta / 2pi = kt . coord)
        ws[KT4 + 4 * i + 0] = fmaf(k0, cinv[0], fmaf(k1, cinv[3], k2 * cinv[6]));
        ws[KT4 + 4 * i + 1] = fmaf(k0, cinv[1], fmaf(k1, cinv[4], k2 * cinv[7]));
        ws[KT4 + 4 * i + 2] = fmaf(k0, cinv[2], fmaf(k1, cinv[5], k2 * cinv[8]));
        ws[KT4 + 4 * i + 3] = 0.f;
    }
    if (i < B * N) {
        ws[AT4 + 4 * i + 0] = coords[3 * i + 0];
        ws[AT4 + 4 * i + 1] = coords[3 * i + 1];
        ws[AT4 + 4 * i + 2] = coords[3 * i + 2];
        ws[AT4 + 4 * i + 3] = q[i];
    }
}

// Pass 1: S_re[b,k] = sum_n q*cos(2pi kt.r), S_im likewise.
// grid (NK/TPB, NS1, B): thread owns one k, block covers TILE1 atoms.
__global__ __launch_bounds__(256) void sf_kernel(float* __restrict__ ws) {
    const int b = blockIdx.z;
    const int k = blockIdx.x * TPB + threadIdx.x;
    const int n0 = blockIdx.y * TILE1;

    const float4 kt = *(const float4*)&ws[KT4 + 4 * k];

    __shared__ float sat[TILE1 * 4];
    sat[threadIdx.x] = ws[AT4 + (size_t)(b * N + n0) * 4 + threadIdx.x];
    __syncthreads();

    const float4* a4 = (const float4*)sat;
    float sre0 = 0.f, sre1 = 0.f, sim0 = 0.f, sim1 = 0.f;
#pragma unroll
    for (int i = 0; i < TILE1; i += 2) {
        float4 a = a4[i];
        float4 c = a4[i + 1];
        float r0 = fmaf(kt.x, a.x, fmaf(kt.y, a.y, kt.z * a.z));
        r0 -= floorf(r0);
        float r1 = fmaf(kt.x, c.x, fmaf(kt.y, c.y, kt.z * c.z));
        r1 -= floorf(r1);
        sre0 = fmaf(a.w, __builtin_amdgcn_cosf(r0), sre0);
        sim0 = fmaf(a.w, __builtin_amdgcn_sinf(r0), sim0);
        sre1 = fmaf(c.w, __builtin_amdgcn_cosf(r1), sre1);
        sim1 = fmaf(c.w, __builtin_amdgcn_sinf(r1), sim1);
    }
    atomicAdd(&ws[SRE + b * NK + k], sre0 + sre1);
    atomicAdd(&ws[SIM + b * NK + k], sim0 + sim1);
}

// scale S by expfac, pack as float2
__global__ __launch_bounds__(256) void pack_kernel(const float* __restrict__ expfac,
                                                   float* __restrict__ ws) {
    int i = blockIdx.x * TPB + threadIdx.x;   // 0 .. B*NK-1
    if (i >= B * NK) return;
    int k = i & (NK - 1);
    float ef = expfac[k];
    ws[SP + 2 * i + 0] = ef * ws[SRE + i];
    ws[SP + 2 * i + 1] = ef * ws[SIM + i];
}

// Pass 2: recip[b,n] = sum_k ef*(Sre*cos + Sim*sin)
// grid (N/TPB, NS2, B): thread owns one atom, block covers TILE2 k's.
__global__ __launch_bounds__(256) void recip_kernel(float* __restrict__ ws) {
    const int b = blockIdx.z;
    const int n = blockIdx.x * TPB + threadIdx.x;
    const int k0 = blockIdx.y * TILE2;

    const float4 at = *(const float4*)&ws[AT4 + (size_t)(b * N + n) * 4];

    __shared__ float skt[TILE2 * 4];
    __shared__ float ssp[TILE2 * 2];
    skt[threadIdx.x] = ws[KT4 + k0 * 4 + threadIdx.x];
    if (threadIdx.x < TILE2 * 2)
        ssp[threadIdx.x] = ws[SP + (size_t)(b * NK + k0) * 2 + threadIdx.x];
    __syncthreads();

    const float4* kt4 = (const float4*)skt;
    const float2* sp2 = (const float2*)ssp;
    float acc0 = 0.f, acc1 = 0.f;
#pragma unroll
    for (int i = 0; i < TILE2; i += 2) {
        float4 kt = kt4[i];
        float2 sp = sp2[i];
        float r0 = fmaf(kt.x, at.x, fmaf(kt.y, at.y, kt.z * at.z));
        r0 -= floorf(r0);
        acc0 = fmaf(sp.x, __builtin_amdgcn_cosf(r0),
                    fmaf(sp.y, __builtin_amdgcn_sinf(r0), acc0));
        float4 kt1 = kt4[i + 1];
        float2 sp1 = sp2[i + 1];
        float r1 = fmaf(kt1.x, at.x, fmaf(kt1.y, at.y, kt1.z * at.z));
        r1 -= floorf(r1);
        acc1 = fmaf(sp1.x, __builtin_amdgcn_cosf(r1),
                    fmaf(sp1.y, __builtin_amdgcn_sinf(r1), acc1));
    }
    atomicAdd(&ws[REC + b * N + n], acc0 + acc1);
}

__global__ __launch_bounds__(256) void final_kernel(const float* __restrict__ q,
                                                    const float* __restrict__ volume,
                                                    const float* __restrict__ bewald,
                                                    const float* __restrict__ ws,
                                                    float* __restrict__ out) {
    int i = blockIdx.x * TPB + threadIdx.x;
    if (i >= B * N) return;
    const float BOHRf = 1.8897261258369282f;
    const float PIf = 3.14159265358979323846f;
    const float inv_sqrt_pi = 0.5641895835477563f;
    float scale = BOHRf / (PIf * volume[0]);
    float self = 2.0f * bewald[0] * BOHRf * inv_sqrt_pi;
    float qv = q[i];
    float phi = ws[REC + i] * scale - qv * self;
    out[i] = 0.5f * qv * phi;
    out[B * N + i] = phi;
}

extern "C" void kernel_launch(void* const* d_in, const int* in_sizes, int n_in,
                              void* d_out, int out_size, void* d_ws, size_t ws_size,
                              hipStream_t stream) {
    const float* coords = (const float*)d_in[0];   // (B,N,3)
    const float* q      = (const float*)d_in[1];   // (B,N)
    const float* cinv   = (const float*)d_in[2];   // (3,3)
    const float* kvec   = (const float*)d_in[3];   // (NK,3)
    const float* expfac = (const float*)d_in[4];   // (NK,)
    const float* volume = (const float*)d_in[5];   // (1,)
    const float* bewald = (const float*)d_in[6];   // (1,)
    float* out = (float*)d_out;
    float* ws  = (float*)d_ws;

    hipMemsetAsync(ws + SRE, 0, (size_t)ZERO_FLOATS * sizeof(float), stream);

    prep_kernel<<<dim3((B * N) / TPB), dim3(TPB), 0, stream>>>(coords, q, cinv, kvec, ws);
    sf_kernel<<<dim3(NK / TPB, NS1, B), dim3(TPB), 0, stream>>>(ws);
    pack_kernel<<<dim3((B * NK) / TPB), dim3(TPB), 0, stream>>>(expfac, ws);
    recip_kernel<<<dim3(N / TPB, NS2, B), dim3(TPB), 0, stream>>>(ws);
    final_kernel<<<dim3((B * N) / TPB), dim3(TPB), 0, stream>>>(q, volume, bewald, ws, out);
}

// Round 3
// 90.392 us; speedup vs baseline: 1.0364x; 1.0364x over previous
//
#include <hip/hip_runtime.h>

// Ewald reciprocal: B=2, N=4096 atoms, NK=4096 k-vectors, all f32.
// out = concat(0.5*q*phi, phi), each B*N floats.
//
// Pass structure (trans-pipe-bound, ~3.4us/pass floor):
//   prep : kt[k] = cell_inv^T kvec[k] packed (kt0,kt1,kt2,ef); atoms packed
//          (x,y,z,q); zero accumulators (no memset needed).
//   sf   : srs[b,k] = ef * (Sre, Sim) via atomic partial sums over atom tiles.
//   recip: rec[b,n] = sum_k (efSre*cos + efSim*sin) via atomic partials over k tiles.
//   final: phi epilogue, two outputs.

constexpr int B   = 2;
constexpr int N   = 4096;
constexpr int NK  = 4096;
constexpr int TPB = 256;
constexpr int NS1 = 64;          // atom-axis split (sf): tile = 64 atoms
constexpr int NS2 = 64;          // k-axis split (recip): tile = 64 k's
constexpr int T1  = N / NS1;
constexpr int T2  = NK / NS2;

// workspace layout (float offsets)
constexpr int KT4 = 0;                   // NK*4   : (kt0,kt1,kt2,expfac)
constexpr int AT4 = KT4 + NK * 4;        // B*N*4  : (x,y,z,q)
constexpr int SRS = AT4 + B * N * 4;     // B*NK*2 : (ef*Sre, ef*Sim) atomic acc
constexpr int REC = SRS + B * NK * 2;    // B*N    : atomic acc
// zero region = SRS..REC end = B*NK*2 + B*N = 24576 floats = 3 per prep thread

__global__ __launch_bounds__(256) void prep_kernel(const float* __restrict__ coords,
                                                   const float* __restrict__ q,
                                                   const float* __restrict__ cinv,
                                                   const float* __restrict__ kvec,
                                                   const float* __restrict__ expfac,
                                                   float* __restrict__ ws) {
    int i = blockIdx.x * TPB + threadIdx.x;   // grid covers exactly B*N = 8192
    if (i < NK) {
        float k0 = kvec[3 * i], k1 = kvec[3 * i + 1], k2 = kvec[3 * i + 2];
        float4 kt;   // kt[j] = sum_d kvec[k,d] * cinv[d,j]; theta/2pi = kt . r
        kt.x = fmaf(k0, cinv[0], fmaf(k1, cinv[3], k2 * cinv[6]));
        kt.y = fmaf(k0, cinv[1], fmaf(k1, cinv[4], k2 * cinv[7]));
        kt.z = fmaf(k0, cinv[2], fmaf(k1, cinv[5], k2 * cinv[8]));
        kt.w = expfac[i];
        *(float4*)&ws[KT4 + 4 * i] = kt;
    }
    {
        float4 a;
        a.x = coords[3 * i]; a.y = coords[3 * i + 1]; a.z = coords[3 * i + 2];
        a.w = q[i];
        *(float4*)&ws[AT4 + 4 * i] = a;
    }
    // zero the atomic accumulators (harness poisons ws with 0xAA each call)
    ws[SRS + 3 * i + 0] = 0.f;
    ws[SRS + 3 * i + 1] = 0.f;
    ws[SRS + 3 * i + 2] = 0.f;
}

// Pass 1: thread owns one k (kt in VGPRs); block sweeps a 64-atom tile via
// block-uniform loads (scalar path). grid (NK/TPB, NS1, B).
__global__ __launch_bounds__(256) void sf_kernel(const float* __restrict__ kt4,
                                                 const float* __restrict__ at4,
                                                 float* __restrict__ srs) {
    const int b = blockIdx.z;
    const int k = blockIdx.x * TPB + threadIdx.x;
    const float4 kt = *(const float4*)&kt4[4 * k];
    const float4* __restrict__ ap =
        (const float4*)&at4[(size_t)(b * N + blockIdx.y * T1) * 4];

    float sre = 0.f, sim = 0.f;
#pragma unroll 8
    for (int i = 0; i < T1; ++i) {
        float4 a = ap[i];                                   // block-uniform
        float r = fmaf(kt.x, a.x, fmaf(kt.y, a.y, kt.z * a.z));
        r -= floorf(r);                                     // v_sin takes revolutions
        sre = fmaf(a.w, __builtin_amdgcn_cosf(r), sre);
        sim = fmaf(a.w, __builtin_amdgcn_sinf(r), sim);
    }
    // fold expfac here: srs accumulates ef*Sre, ef*Sim
    atomicAdd(&srs[2 * (b * NK + k) + 0], kt.w * sre);
    atomicAdd(&srs[2 * (b * NK + k) + 1], kt.w * sim);
}

// Pass 2: thread owns one atom (coords in VGPRs); block sweeps a 64-k tile via
// block-uniform loads. grid (N/TPB, NS2, B).
__global__ __launch_bounds__(256) void recip_kernel(const float* __restrict__ kt4,
                                                    const float* __restrict__ at4,
                                                    const float* __restrict__ srs,
                                                    float* __restrict__ rec) {
    const int b = blockIdx.z;
    const int n = blockIdx.x * TPB + threadIdx.x;
    const float4 at = *(const float4*)&at4[(size_t)(b * N + n) * 4];
    const int k0 = blockIdx.y * T2;
    const float4* __restrict__ kp = (const float4*)&kt4[4 * k0];
    const float2* __restrict__ sp = (const float2*)&srs[2 * (b * NK + k0)];

    float acc = 0.f;
#pragma unroll 8
    for (int i = 0; i < T2; ++i) {
        float4 kt = kp[i];                                  // block-uniform
        float2 s  = sp[i];                                  // block-uniform
        float r = fmaf(kt.x, at.x, fmaf(kt.y, at.y, kt.z * at.z));
        r -= floorf(r);
        acc = fmaf(s.x, __builtin_amdgcn_cosf(r),
                   fmaf(s.y, __builtin_amdgcn_sinf(r), acc));
    }
    atomicAdd(&rec[b * N + n], acc);
}

__global__ __launch_bounds__(256) void final_kernel(const float* __restrict__ q,
                                                    const float* __restrict__ volume,
                                                    const float* __restrict__ bewald,
                                                    const float* __restrict__ rec,
                                                    float* __restrict__ out) {
    int i = blockIdx.x * TPB + threadIdx.x;
    if (i >= B * N) return;
    const float BOHRf = 1.8897261258369282f;
    const float PIf = 3.14159265358979323846f;
    const float inv_sqrt_pi = 0.5641895835477563f;
    float scale = BOHRf / (PIf * volume[0]);
    float self = 2.0f * bewald[0] * BOHRf * inv_sqrt_pi;
    float qv = q[i];
    float phi = rec[i] * scale - qv * self;
    out[i] = 0.5f * qv * phi;
    out[B * N + i] = phi;
}

extern "C" void kernel_launch(void* const* d_in, const int* in_sizes, int n_in,
                              void* d_out, int out_size, void* d_ws, size_t ws_size,
                              hipStream_t stream) {
    const float* coords = (const float*)d_in[0];   // (B,N,3)
    const float* q      = (const float*)d_in[1];   // (B,N)
    const float* cinv   = (const float*)d_in[2];   // (3,3)
    const float* kvec   = (const float*)d_in[3];   // (NK,3)
    const float* expfac = (const float*)d_in[4];   // (NK,)
    const float* volume = (const float*)d_in[5];   // (1,)
    const float* bewald = (const float*)d_in[6];   // (1,)
    float* out = (float*)d_out;
    float* ws  = (float*)d_ws;

    prep_kernel<<<dim3((B * N) / TPB), dim3(TPB), 0, stream>>>(coords, q, cinv,
                                                               kvec, expfac, ws);
    sf_kernel<<<dim3(NK / TPB, NS1, B), dim3(TPB), 0, stream>>>(ws + KT4, ws + AT4,
                                                                ws + SRS);
    recip_kernel<<<dim3(N / TPB, NS2, B), dim3(TPB), 0, stream>>>(ws + KT4, ws + AT4,
                                                                  ws + SRS, ws + REC);
    final_kernel<<<dim3((B * N) / TPB), dim3(TPB), 0, stream>>>(q, volume, bewald,
                                                                ws + REC, out);
}